// Round 2
// baseline (237.919 us; speedup 1.0000x reference)
//
#include <hip/hip_runtime.h>

// Elementwise clamp: out = min(max(x, lo), hi)
// x: 33,554,432 fp32 (4194304 x 8). Pure streaming kernel:
// 128 MiB read + 128 MiB write = 268 MB -> ~42.6 us floor at 6.3 TB/s.
//
// R2: A/B vs R1 — identical structure, nontemporal REMOVED (suspect for
// R1's -2% regression; the 6.3 TB/s m13 ceiling was measured with regular
// cached float4 copy, and the harness fills hit 6.75 TB/s through the
// normal L2 allocate path).
//  - 2048 blocks x 256 threads = 8192 waves = 100% of device wave slots,
//    grid-stride (Guideline 11 streaming config).
//  - 4 independent float4 accesses in flight per thread (ILP for latency
//    hiding on top of full TLP).

typedef float f32x4 __attribute__((ext_vector_type(4)));

__device__ __forceinline__ f32x4 clamp4(f32x4 v, float lo, float hi) {
    // fminf(fmaxf(..)) -> v_med3_f32 clamp idiom
    v.x = fminf(fmaxf(v.x, lo), hi);
    v.y = fminf(fmaxf(v.y, lo), hi);
    v.z = fminf(fmaxf(v.z, lo), hi);
    v.w = fminf(fmaxf(v.w, lo), hi);
    return v;
}

__global__ void __launch_bounds__(256) clamp_kernel(
    const f32x4* __restrict__ x,
    const float* __restrict__ cp,
    f32x4* __restrict__ out,
    int n4)
{
    const float lo = cp[0];
    const float hi = cp[1];
    const int stride = gridDim.x * blockDim.x;
    int i = blockIdx.x * blockDim.x + threadIdx.x;

    // Main loop: 4 independent 16B loads in flight per thread.
    for (; i + 3 * stride < n4; i += 4 * stride) {
        f32x4 v0 = x[i];
        f32x4 v1 = x[i + stride];
        f32x4 v2 = x[i + 2 * stride];
        f32x4 v3 = x[i + 3 * stride];
        out[i]              = clamp4(v0, lo, hi);
        out[i + stride]     = clamp4(v1, lo, hi);
        out[i + 2 * stride] = clamp4(v2, lo, hi);
        out[i + 3 * stride] = clamp4(v3, lo, hi);
    }
    // Tail (exact fit at 2048x256 for n4 = 8,388,608, but stay general).
    for (; i < n4; i += stride) {
        out[i] = clamp4(x[i], lo, hi);
    }
}

extern "C" void kernel_launch(void* const* d_in, const int* in_sizes, int n_in,
                              void* d_out, int out_size, void* d_ws, size_t ws_size,
                              hipStream_t stream)
{
    const f32x4* x = (const f32x4*)d_in[0];
    const float* cp = (const float*)d_in[1];
    f32x4* out = (f32x4*)d_out;

    const int n = in_sizes[0];          // 33,554,432 fp32 elements
    const int n4 = n / 4;               // 8,388,608 float4s (exact)

    const int block = 256;
    int grid = 2048;                    // 8 blocks/CU, grid-stride the rest
    const int needed = (n4 + block - 1) / block;
    if (grid > needed) grid = needed;
    if (grid < 1) grid = 1;

    clamp_kernel<<<grid, block, 0, stream>>>(x, cp, out, n4);
}

// Round 4
// 228.161 us; speedup vs baseline: 1.0428x; 1.0428x over previous
//
#include <hip/hip_runtime.h>

// Elementwise clamp: out = min(max(x, lo), hi)
// x: 33,554,432 fp32 (4194304 x 8). Pure streaming kernel:
// 128 MiB read + 128 MiB write = 268 MB -> ~42.7 us floor at 6.29 TB/s
// (m13 float4-copy ceiling, same read+write mix).
//
// R4 = R3 resubmitted verbatim (R3 was an infra failure: "container failed
// twice" — kernel never ran; keep the A/B vs R2 clean).
//
// Kill the vmcnt store->load serialization seen in R2 (85 us, 2.4 TB/s,
// VALUBusy 4%). Loads and stores share vmcnt and retire IN ISSUE ORDER on
// CDNA; R2's grid-stride loop issued loads AFTER the previous iteration's
// stores, so each iteration's s_waitcnt could only clear after the prior
// stores completed -> loop ran at HBM round-trip latency, not BW.
// Structure now: per thread, 8 independent global_load_dwordx4 issued
// back-to-back (NO store precedes any load), one wait, clamp, 8 stores.
// 4096 blocks x 256 threads x 8 float4 = 8,388,608 float4s exact.

typedef float f32x4 __attribute__((ext_vector_type(4)));

#define PT 8          // float4s per thread
#define BLOCK 256

__device__ __forceinline__ f32x4 clamp4(f32x4 v, float lo, float hi) {
    // fminf(fmaxf(..)) -> v_med3_f32 clamp idiom
    v.x = fminf(fmaxf(v.x, lo), hi);
    v.y = fminf(fmaxf(v.y, lo), hi);
    v.z = fminf(fmaxf(v.z, lo), hi);
    v.w = fminf(fmaxf(v.w, lo), hi);
    return v;
}

__global__ void __launch_bounds__(BLOCK) clamp_kernel(
    const f32x4* __restrict__ x,
    const float* __restrict__ cp,
    f32x4* __restrict__ out,
    int n4)
{
    const float lo = cp[0];
    const float hi = cp[1];
    const int base = blockIdx.x * (BLOCK * PT) + threadIdx.x;

    if (base + (PT - 1) * BLOCK < n4) {
        // Fast path: 8 loads in flight, zero stores before any load.
        f32x4 v[PT];
#pragma unroll
        for (int k = 0; k < PT; ++k)
            v[k] = x[base + k * BLOCK];
#pragma unroll
        for (int k = 0; k < PT; ++k)
            out[base + k * BLOCK] = clamp4(v[k], lo, hi);
    } else {
        // Guarded tail (not taken at the exact 4194304x8 shape).
#pragma unroll
        for (int k = 0; k < PT; ++k) {
            int idx = base + k * BLOCK;
            if (idx < n4)
                out[idx] = clamp4(x[idx], lo, hi);
        }
    }
}

extern "C" void kernel_launch(void* const* d_in, const int* in_sizes, int n_in,
                              void* d_out, int out_size, void* d_ws, size_t ws_size,
                              hipStream_t stream)
{
    const f32x4* x = (const f32x4*)d_in[0];
    const float* cp = (const float*)d_in[1];
    f32x4* out = (f32x4*)d_out;

    const int n = in_sizes[0];          // 33,554,432 fp32 elements
    const int n4 = n / 4;               // 8,388,608 float4s (exact)

    const int per_block = BLOCK * PT;   // 2048 float4s per block
    const int grid = (n4 + per_block - 1) / per_block;   // 4096 blocks

    clamp_kernel<<<grid, BLOCK, 0, stream>>>(x, cp, out, n4);
}